// Round 1
// baseline (26147.736 us; speedup 1.0000x reference)
//
#include <hip/hip_runtime.h>
#include <hip/hip_bf16.h>

// Problem constants
#define NB 32      // batch
#define TD 128     // decode steps
#define SE 256     // encoder length
#define HD 512     // hidden
#define EEnc 512   // encoder dim
#define EMB 256    // embedding dim
#define NV 32000   // vocab

typedef __attribute__((ext_vector_type(8))) short bf16x8;
typedef __attribute__((ext_vector_type(4))) float f32x4;

__device__ __forceinline__ float fsigm(float x){ return 1.f/(1.f+__expf(-x)); }
__device__ __forceinline__ float ftanh(float x){
  float c = fminf(fmaxf(x,-15.f),15.f);
  float e = __expf(2.f*c);
  return (e-1.f)/(e+1.f);
}

// ---------------- workspace float offsets ----------------
// kp      0          (4,194,304)
// emb_g   4,194,304  (1,048,576)
// qw      5,242,880  (16,384)
// scores  5,259,264  (8,192)
// ctx     5,267,456  (16,384)
// h0pp    5,283,840  (2 x 16,384)   <- zero region start
// h1pp    5,316,608  (2 x 16,384)
// c0      5,349,376  (16,384)
// c1      5,365,760  (16,384)
// bars    5,382,144  (1,024)        <- zero region end (99,328 total)
// WqT     5,383,168  (262,144)
// Wi0     5,645,312  (2,621,440)    row-interleaved u*4+gate, K=1280
// Wi1     8,266,752  (2,097,152)    row-interleaved u*4+gate, K=1024
// bi0     10,363,904 (2,048)
// bi1     10,365,952 (2,048)
// X bf16 at byte 44,548,096 ; Wout bf16 at byte 52,936,704 (unchanged)

// ---------------- prologue kernels ----------------

__global__ __launch_bounds__(256) void k_init(float* z){
  z[(size_t)blockIdx.x*256 + threadIdx.x] = 0.f;
}

__global__ __launch_bounds__(256) void k_gather(const float* __restrict__ emb, const int* __restrict__ tok,
                                                float* __restrict__ emb_g){
  int row = blockIdx.x;                       // b*TD + t
  int tk = tok[row];
  emb_g[(size_t)row*EMB + threadIdx.x] = emb[(size_t)tk*EMB + threadIdx.x];
}

// key_proj = enc @ Wk^T + bk : M=8192 (b,s), N=512 (h), K=512. fp32 classic tile GEMM.
__global__ __launch_bounds__(256) void k_keyproj(const float* __restrict__ enc, const float* __restrict__ Wk,
                                                 const float* __restrict__ bk, float* __restrict__ kp){
  __shared__ float As[16][136];
  __shared__ float Bs[16*164];
  int tid = threadIdx.x;
  int bn = blockIdx.x, bm = blockIdx.y;
  int tx = tid & 15, ty = tid >> 4;
  float acc[8][8];
  #pragma unroll
  for (int i=0;i<8;i++)
    #pragma unroll
    for (int j=0;j<8;j++) acc[i][j]=0.f;
  for (int k0=0;k0<512;k0+=16){
    __syncthreads();
    #pragma unroll
    for (int r=0;r<8;r++){
      int idx = tid + r*256;
      int row = idx >> 4, kk = idx & 15;
      As[kk][row] = enc[(size_t)(bm*128+row)*EEnc + k0 + kk];
      float wv = Wk[(size_t)(bn*128+row)*EEnc + k0 + kk];
      Bs[(row>>3)*164 + kk*8 + (row&7)] = wv;
    }
    __syncthreads();
    #pragma unroll 4
    for (int kk=0;kk<16;kk++){
      float a[8], b[8];
      *(float4*)(a)   = *(float4*)&As[kk][ty*8];
      *(float4*)(a+4) = *(float4*)&As[kk][ty*8+4];
      *(float4*)(b)   = *(float4*)&Bs[tx*164 + kk*8];
      *(float4*)(b+4) = *(float4*)&Bs[tx*164 + kk*8 + 4];
      #pragma unroll
      for (int i=0;i<8;i++)
        #pragma unroll
        for (int j=0;j<8;j++) acc[i][j] += a[i]*b[j];
    }
  }
  #pragma unroll
  for (int i=0;i<8;i++){
    int row = bm*128 + ty*8 + i;
    #pragma unroll
    for (int j=0;j<8;j++){
      int col = bn*128 + tx*8 + j;
      kp[(size_t)row*HD + col] = acc[i][j] + bk[col];
    }
  }
}

// Gate-interleaved concat weights: dst row jr = u*4 + gate (gate = j>>9, u = j&511).
// Wi0[jr][0:768]=Wih0[j], [768:1280]=Whh0[j]; bi0[jr] = bih0[j]+bhh0[j].
__global__ __launch_bounds__(256) void k_wcat0(const float* __restrict__ Wih, const float* __restrict__ Whh,
                                               const float* __restrict__ bih, const float* __restrict__ bhh,
                                               float* __restrict__ Wi, float* __restrict__ bi){
  int j = blockIdx.x;
  int jr = (j & 511)*4 + (j >> 9);
  for (int k=threadIdx.x;k<1280;k+=256){
    float v = (k<768) ? Wih[(size_t)j*768+k] : Whh[(size_t)j*512 + (k-768)];
    Wi[(size_t)jr*1280+k] = v;
  }
  if (threadIdx.x==0) bi[jr] = bih[j]+bhh[j];
}
__global__ __launch_bounds__(256) void k_wcat1(const float* __restrict__ Wih, const float* __restrict__ Whh,
                                               const float* __restrict__ bih, const float* __restrict__ bhh,
                                               float* __restrict__ Wi, float* __restrict__ bi){
  int j = blockIdx.x;
  int jr = (j & 511)*4 + (j >> 9);
  for (int k=threadIdx.x;k<1024;k+=256){
    float v = (k<512) ? Wih[(size_t)j*512+k] : Whh[(size_t)j*512 + (k-512)];
    Wi[(size_t)jr*1024+k] = v;
  }
  if (threadIdx.x==0) bi[jr] = bih[j]+bhh[j];
}

// Wq transpose: WqT[e][h] = Wq[h][e]
__global__ __launch_bounds__(256) void k_trq(const float* __restrict__ W, float* __restrict__ WT){
  __shared__ float t[32][33];
  int h0 = blockIdx.x*32, e0 = blockIdx.y*32;
  int x = threadIdx.x & 31, y = threadIdx.x >> 5;
  for (int r=y; r<32; r+=8) t[r][x] = W[(size_t)(h0+r)*512 + e0+x];
  __syncthreads();
  for (int r=y; r<32; r+=8) WT[(size_t)(e0+r)*512 + h0+x] = t[x][r];
}

// Wout fp32 -> bf16 (one row per block)
__global__ __launch_bounds__(256) void k_cvtw(const float* __restrict__ W, unsigned short* __restrict__ Wb){
  size_t base = (size_t)blockIdx.x*1024 + threadIdx.x*4;
  float4 v = *(const float4*)(W + base);
  __hip_bfloat16 b0 = __float2bfloat16(v.x), b1 = __float2bfloat16(v.y);
  __hip_bfloat16 b2 = __float2bfloat16(v.z), b3 = __float2bfloat16(v.w);
  ushort4 o;
  o.x = *(unsigned short*)&b0; o.y = *(unsigned short*)&b1;
  o.z = *(unsigned short*)&b2; o.w = *(unsigned short*)&b3;
  *(ushort4*)(Wb + base) = o;
}

// ---------------- persistent recurrence kernel ----------------
// 256 blocks x 256 threads = 1 block/CU (co-residency by capacity; no cooperative
// launch required). 4 groups of 64 blocks; group g owns batches [g*8, g*8+8).
// Group-local two-level sense-reversal barrier (8 sub-counters of 8 + root).

__device__ __forceinline__ void gbar(unsigned* bar, int lb, unsigned &sense){
  __syncthreads();
  if (threadIdx.x == 0){
    sense ^= 1u;
    __threadfence();   // release this block's phase writes (agent scope)
    unsigned* subc = bar + 16 + (lb >> 3)*16;   // 64B-separated sub counters
    unsigned p = __hip_atomic_fetch_add(subc, 1u, __ATOMIC_ACQ_REL, __HIP_MEMORY_SCOPE_AGENT);
    if (p == 7u){
      __hip_atomic_store(subc, 0u, __ATOMIC_RELAXED, __HIP_MEMORY_SCOPE_AGENT);
      unsigned q = __hip_atomic_fetch_add(bar, 1u, __ATOMIC_ACQ_REL, __HIP_MEMORY_SCOPE_AGENT);
      if (q == 7u){
        __hip_atomic_store(bar, 0u, __ATOMIC_RELAXED, __HIP_MEMORY_SCOPE_AGENT);
        __hip_atomic_store(bar + 1, sense, __ATOMIC_RELEASE, __HIP_MEMORY_SCOPE_AGENT);
      }
    }
    while (__hip_atomic_load(bar + 1, __ATOMIC_ACQUIRE, __HIP_MEMORY_SCOPE_AGENT) != sense)
      __builtin_amdgcn_s_sleep(2);
    __threadfence();   // acquire side
  }
  __syncthreads();
}

__global__ __launch_bounds__(256) void k_step(const float* __restrict__ enc,
                                              const float* __restrict__ bq,
                                              const float* __restrict__ vv,
                                              float* __restrict__ wsf,
                                              float* __restrict__ out){
  const float* kp    = wsf;
  const float* emb_g = wsf + 4194304;
  float* qw     = wsf + 5242880;
  float* scores = wsf + 5259264;
  float* ctx    = wsf + 5267456;
  float* h0pp   = wsf + 5283840;
  float* h1pp   = wsf + 5316608;
  float* c0     = wsf + 5349376;
  float* c1     = wsf + 5365760;
  unsigned* bars= (unsigned*)(wsf + 5382144);
  const float* WqT = wsf + 5383168;
  const float* Wi0 = wsf + 5645312;
  const float* Wi1 = wsf + 8266752;
  const float* bi0 = wsf + 10363904;
  const float* bi1 = wsf + 10365952;
  __hip_bfloat16* X = (__hip_bfloat16*)((char*)wsf + 44548096);

  const int gid = blockIdx.x;
  const int grp = gid >> 6;       // 0..3
  const int lb  = gid & 63;       // 0..63
  const int tid = threadIdx.x;
  unsigned* bar = bars + grp*256;
  unsigned sense = 0;

  __shared__ __align__(16) float xs[10240];   // x-vectors / h1 stage
  __shared__ __align__(16) float red[2176];   // cross-thread reductions
  __shared__ __align__(16) float aux[1088];   // qw/v/softmax weights

  for (int t=0; t<TD; t++){
    const int p = t & 1;
    const float* h1p = h1pp + p*16384;        // h1_{t-1}
    float*       h1n = h1pp + (p^1)*16384;    // h1_t
    const float* h0p = h0pp + p*16384;        // h0_{t-1}
    float*       h0n = h0pp + (p^1)*16384;    // h0_t

    // ---- A: qw[b][h] = bq + Wq @ h1_{t-1}; block lb owns h in [lb*8, lb*8+8), all 8 b
    {
      #pragma unroll
      for (int bL=0; bL<8; bL++){
        int bb = grp*8 + bL;
        for (int e=tid; e<HD; e+=256) xs[bL*520 + e] = h1p[(size_t)bb*HD + e];
      }
      __syncthreads();
      int hL = tid & 7, sp = tid >> 3;        // 8 h x 32 e-slices of 16
      const float* wp = WqT + (size_t)(sp*16)*HD + lb*8 + hL;
      float a[8];
      #pragma unroll
      for (int i=0;i<8;i++) a[i]=0.f;
      #pragma unroll
      for (int e=0;e<16;e++){
        float w = wp[(size_t)e*HD];
        #pragma unroll
        for (int bL=0;bL<8;bL++) a[bL] += w * xs[bL*520 + sp*16 + e];
      }
      #pragma unroll
      for (int bL=0;bL<8;bL++) red[(hL*8+bL)*34 + sp] = a[bL];
      __syncthreads();
      if (tid < 64){
        int hL2 = tid >> 3, bL2 = tid & 7;
        const float* pr = red + (hL2*8+bL2)*34;
        float s = bq[lb*8 + hL2];
        #pragma unroll
        for (int q2=0;q2<32;q2++) s += pr[q2];
        qw[(size_t)(grp*8+bL2)*HD + lb*8 + hL2] = s;
      }
    }
    gbar(bar, lb, sense);

    // ---- B: scores[b][s] = sum_h tanh(kp + qw) * v ; block (sc=lb>>3, bl=lb&7), 32 s
    {
      int sc = lb >> 3;
      int bb = grp*8 + (lb & 7);
      aux[tid]       = qw[(size_t)bb*HD + tid];
      aux[tid + 256] = qw[(size_t)bb*HD + tid + 256];
      aux[tid + 512] = vv[tid];
      aux[tid + 768] = vv[tid + 256];
      __syncthreads();
      int lane = tid & 63, wv = tid >> 6;
      #pragma unroll
      for (int si=0; si<8; si++){
        int s = sc*32 + wv*8 + si;
        const float* row = kp + ((size_t)bb*SE + s)*HD;
        float acc = 0.f;
        #pragma unroll
        for (int i=0;i<8;i++){
          int h = lane + i*64;
          acc += ftanh(row[h] + aux[h]) * aux[512 + h];
        }
        for (int o=32;o;o>>=1) acc += __shfl_down(acc, o);
        if (lane==0) scores[(size_t)bb*SE + s] = acc;
      }
    }
    gbar(bar, lb, sense);

    // ---- C: softmax + ctx[b][e] ; block (ec=lb>>3, bl=lb&7), 64 e
    {
      int ec = lb >> 3;
      int bb = grp*8 + (lb & 7);
      int lane = tid & 63, wv = tid >> 6;
      float sv = scores[(size_t)bb*SE + tid];
      float m = sv;
      for (int o=32;o;o>>=1) m = fmaxf(m, __shfl_xor(m, o));
      if (lane==0) red[wv] = m;
      __syncthreads();
      m = fmaxf(fmaxf(red[0],red[1]), fmaxf(red[2],red[3]));
      float ex = __expf(sv - m);
      aux[tid] = ex;
      float sum = ex;
      for (int o=32;o;o>>=1) sum += __shfl_xor(sum, o);
      if (lane==0) red[8+wv] = sum;
      __syncthreads();
      float inv = 1.f/(red[8]+red[9]+red[10]+red[11]);
      const float* ep = enc + ((size_t)bb*SE + wv*64)*EEnc + ec*64 + lane;
      const float* wl = aux + wv*64;
      float acc = 0.f;
      #pragma unroll 4
      for (int s=0;s<64;s++) acc += wl[s] * ep[(size_t)s*EEnc];
      red[16 + wv*64 + lane] = acc;
      __syncthreads();
      if (tid < 64){
        float c = (red[16+tid]+red[80+tid]+red[144+tid]+red[208+tid]) * inv;
        ctx[(size_t)bb*HD + ec*64 + tid] = c;
        X[((size_t)bb*TD + t)*1024 + 512 + ec*64 + tid] = __float2bfloat16(c);
      }
    }
    gbar(bar, lb, sense);

    // ---- D: gates0 (full K=1280) + h0/c0 activation; block lb owns rows
    //      [lb*32, lb*32+32) of gate-interleaved Wi0 (= u in [lb*8,lb*8+8), 4 gates), all 8 b
    {
      #pragma unroll
      for (int bL=0; bL<8; bL++){
        int bb = grp*8 + bL;
        for (int k=tid; k<1280; k+=256){
          float v;
          if (k < 256)      v = emb_g[((size_t)bb*TD + t)*EMB + k];
          else if (k < 768) v = ctx[(size_t)bb*HD + (k-256)];
          else              v = h0p[(size_t)bb*HD + (k-768)];
          xs[bL*1280 + k] = v;
        }
      }
      __syncthreads();
      int r = tid & 31, kq = tid >> 5;         // 32 rows x 8 k-slices of 160
      const float* wrow = Wi0 + (size_t)(lb*32 + r)*1280 + kq*160;
      float a[8];
      #pragma unroll
      for (int i=0;i<8;i++) a[i]=0.f;
      #pragma unroll 2
      for (int k=0;k<160;k+=4){
        float4 w4 = *(const float4*)(wrow + k);
        #pragma unroll
        for (int bL=0;bL<8;bL++){
          float4 x4 = *(const float4*)&xs[bL*1280 + kq*160 + k];
          a[bL] += w4.x*x4.x + w4.y*x4.y + w4.z*x4.z + w4.w*x4.w;
        }
      }
      #pragma unroll
      for (int bL=0;bL<8;bL++) red[(bL*8+kq)*34 + r] = a[bL];
      __syncthreads();
      if (tid < 64){
        int uL = tid >> 3, bL = tid & 7;
        int u = lb*8 + uL, bb = grp*8 + bL;
        float gi = bi0[u*4+0], gf = bi0[u*4+1], gg = bi0[u*4+2], go = bi0[u*4+3];
        #pragma unroll
        for (int q=0;q<8;q++){
          const float* pr = red + (bL*8+q)*34 + uL*4;
          gi += pr[0]; gf += pr[1]; gg += pr[2]; go += pr[3];
        }
        float cp = c0[(size_t)bb*HD + u];
        float cn = fsigm(gf)*cp + fsigm(gi)*ftanh(gg);
        float hn = fsigm(go)*ftanh(cn);
        c0[(size_t)bb*HD + u] = cn;
        h0n[(size_t)bb*HD + u] = hn;
      }
    }
    gbar(bar, lb, sense);

    // ---- E: gates1 (full K=1024, x=[h0_t | h1_{t-1}]) + h1/c1 activation + X write
    {
      #pragma unroll
      for (int bL=0; bL<8; bL++){
        int bb = grp*8 + bL;
        for (int k=tid; k<1024; k+=256){
          float v = (k < 512) ? h0n[(size_t)bb*HD + k] : h1p[(size_t)bb*HD + (k-512)];
          xs[bL*1024 + k] = v;
        }
      }
      __syncthreads();
      int r = tid & 31, kq = tid >> 5;         // 32 rows x 8 k-slices of 128
      const float* wrow = Wi1 + (size_t)(lb*32 + r)*1024 + kq*128;
      float a[8];
      #pragma unroll
      for (int i=0;i<8;i++) a[i]=0.f;
      #pragma unroll 2
      for (int k=0;k<128;k+=4){
        float4 w4 = *(const float4*)(wrow + k);
        #pragma unroll
        for (int bL=0;bL<8;bL++){
          float4 x4 = *(const float4*)&xs[bL*1024 + kq*128 + k];
          a[bL] += w4.x*x4.x + w4.y*x4.y + w4.z*x4.z + w4.w*x4.w;
        }
      }
      #pragma unroll
      for (int bL=0;bL<8;bL++) red[(bL*8+kq)*34 + r] = a[bL];
      __syncthreads();
      if (tid < 64){
        int uL = tid >> 3, bL = tid & 7;
        int u = lb*8 + uL, bb = grp*8 + bL;
        float gi = bi1[u*4+0], gf = bi1[u*4+1], gg = bi1[u*4+2], go = bi1[u*4+3];
        #pragma unroll
        for (int q=0;q<8;q++){
          const float* pr = red + (bL*8+q)*34 + uL*4;
          gi += pr[0]; gf += pr[1]; gg += pr[2]; go += pr[3];
        }
        float cp = c1[(size_t)bb*HD + u];
        float cn = fsigm(gf)*cp + fsigm(gi)*ftanh(gg);
        float hn = fsigm(go)*ftanh(cn);
        c1[(size_t)bb*HD + u] = cn;
        h1n[(size_t)bb*HD + u] = hn;
        X[((size_t)bb*TD + t)*1024 + u] = __float2bfloat16(hn);
      }
    }
    gbar(bar, lb, sense);
  }

  // epilogue: TD even -> final h0/h1 live in ping 0; copy h,c output sections
  if (lb < 8){
    int bb = grp*8 + lb;
    const size_t OUT_H = (size_t)NB*TD*NV;
    const size_t OUT_C = OUT_H + (size_t)2*NB*HD;
    for (int e=tid; e<HD; e+=256){
      size_t base = (size_t)bb*HD + e;
      out[OUT_H + base]                 = h0pp[base];   // h[0]
      out[OUT_H + (size_t)NB*HD + base] = h1pp[base];   // h[1]
      out[OUT_C + base]                 = c0[base];     // c[0]
      out[OUT_C + (size_t)NB*HD + base] = c1[base];     // c[1]
    }
  }
}

// ---------------- logits GEMM (unchanged, verified) ----------------
__global__ __launch_bounds__(256) void k_gemm(const unsigned short* __restrict__ X,
                                              const unsigned short* __restrict__ W,
                                              const float* __restrict__ bout, float* __restrict__ out){
  __shared__ unsigned short As[128][64];
  __shared__ unsigned short Bs[128][64];
  int tid = threadIdx.x;
  int bn = blockIdx.x, bm = blockIdx.y;
  int wave = tid>>6, lane = tid&63;
  int wm = wave&1, wn = wave>>1;
  int r16 = lane&15, quad = lane>>4;
  f32x4 acc[4][4];
  #pragma unroll
  for (int i=0;i<4;i++)
    #pragma unroll
    for (int j=0;j<4;j++){ f32x4 z = {0.f,0.f,0.f,0.f}; acc[i][j] = z; }
  for (int k0=0;k0<1024;k0+=64){
    __syncthreads();
    #pragma unroll
    for (int i=0;i<4;i++){
      int idx = tid + i*256;
      int row = idx>>3, ch = idx&7;
      int sw = ch ^ (row&7);
      *(uint4*)&As[row][sw*8] = *(const uint4*)(X + (size_t)(bm*128+row)*1024 + k0 + ch*8);
      *(uint4*)&Bs[row][sw*8] = *(const uint4*)(W + (size_t)(bn*128+row)*1024 + k0 + ch*8);
    }
    __syncthreads();
    #pragma unroll
    for (int kk=0;kk<2;kk++){
      bf16x8 af[4], bf[4];
      #pragma unroll
      for (int i=0;i<4;i++){
        int ar = wm*64 + i*16 + r16;
        int ach = (kk*4 + quad) ^ (ar&7);
        af[i] = *(bf16x8*)&As[ar][ach*8];
        int br = wn*64 + i*16 + r16;
        int bch = (kk*4 + quad) ^ (br&7);
        bf[i] = *(bf16x8*)&Bs[br][bch*8];
      }
      #pragma unroll
      for (int i=0;i<4;i++)
        #pragma unroll
        for (int j=0;j<4;j++)
          acc[i][j] = __builtin_amdgcn_mfma_f32_16x16x32_bf16(af[i], bf[j], acc[i][j], 0,0,0);
    }
  }
  #pragma unroll
  for (int j=0;j<4;j++){
    int col = bn*128 + wn*64 + j*16 + r16;
    float bo = bout[col];
    #pragma unroll
    for (int i=0;i<4;i++){
      int row0 = bm*128 + wm*64 + i*16 + quad*4;
      #pragma unroll
      for (int r=0;r<4;r++)
        out[(size_t)(row0+r)*NV + col] = acc[i][j][r] + bo;
    }
  }
}

// ---------------- launch ----------------

extern "C" void kernel_launch(void* const* d_in, const int* in_sizes, int n_in,
                              void* d_out, int out_size, void* d_ws, size_t ws_size,
                              hipStream_t stream){
  (void)in_sizes; (void)n_in; (void)out_size; (void)ws_size;
  const float* enc  = (const float*)d_in[0];
  const int*   tok  = (const int*)d_in[1];
  const float* emb  = (const float*)d_in[2];
  const float* Wq   = (const float*)d_in[3];
  const float* bq   = (const float*)d_in[4];
  const float* Wk   = (const float*)d_in[5];
  const float* bk   = (const float*)d_in[6];
  const float* vv   = (const float*)d_in[7];
  const float* Wih0 = (const float*)d_in[8];
  const float* Whh0 = (const float*)d_in[9];
  const float* bih0 = (const float*)d_in[10];
  const float* bhh0 = (const float*)d_in[11];
  const float* Wih1 = (const float*)d_in[12];
  const float* Whh1 = (const float*)d_in[13];
  const float* bih1 = (const float*)d_in[14];
  const float* bhh1 = (const float*)d_in[15];
  const float* Wout = (const float*)d_in[16];
  const float* bout = (const float*)d_in[17];
  float* out = (float*)d_out;

  float* wsf = (float*)d_ws;
  float* kp    = wsf + 0;
  float* emb_g = wsf + 4194304;
  float* WqT   = wsf + 5383168;
  float* Wi0   = wsf + 5645312;
  float* Wi1   = wsf + 8266752;
  float* bi0   = wsf + 10363904;
  float* bi1   = wsf + 10365952;
  char* wsb = (char*)d_ws;
  __hip_bfloat16* X = (__hip_bfloat16*)(wsb + 44548096);
  unsigned short* Woutb = (unsigned short*)(wsb + 52936704);

  // prologue
  hipLaunchKernelGGL(k_init,   dim3(388),  dim3(256), 0, stream, wsf + 5283840); // h0/h1/c0/c1/bars
  hipLaunchKernelGGL(k_gather, dim3(NB*TD),dim3(256), 0, stream, emb, tok, emb_g);
  hipLaunchKernelGGL(k_keyproj,dim3(4,64), dim3(256), 0, stream, enc, Wk, bk, kp);
  hipLaunchKernelGGL(k_wcat0,  dim3(2048), dim3(256), 0, stream, Wih0, Whh0, bih0, bhh0, Wi0, bi0);
  hipLaunchKernelGGL(k_wcat1,  dim3(2048), dim3(256), 0, stream, Wih1, Whh1, bih1, bhh1, Wi1, bi1);
  hipLaunchKernelGGL(k_trq,    dim3(16,16),dim3(256), 0, stream, Wq, WqT);
  hipLaunchKernelGGL(k_cvtw,   dim3(NV),   dim3(256), 0, stream, Wout, Woutb);

  // full 128-step recurrence in one persistent kernel (256 blocks = 1/CU)
  hipLaunchKernelGGL(k_step, dim3(256), dim3(256), 0, stream, enc, bq, vv, wsf, out);

  // logits
  hipLaunchKernelGGL(k_gemm, dim3(NV/128, (NB*TD)/128), dim3(256), 0, stream,
                     (const unsigned short*)X, Woutb, bout, out);
}